// Round 1
// baseline (3319.426 us; speedup 1.0000x reference)
//
#include <hip/hip_runtime.h>
#include <cstdint>
#include <cstddef>

// BitSAE: x' = x - dec_b
//         f  = relu(actq(x') @ tern(enc_w)^T + enc_b)     [4096, 32768]
//         xh = actq(f) @ tern(dec_w)^T + dec_b            [4096, 4096]
// actq: per-row int8 absmax quant (value = q * clip(max,EPS)/127)
// tern: per-tensor ternary absmean quant (value = t * clip(mean|w|,EPS), t in {-1,0,1})
// => integer GEMMs via mfma_i32_16x16x64_i8, scales applied in epilogue.

#define EPS_F 1e-5f

typedef int   i32x4 __attribute__((ext_vector_type(4)));
typedef float f32x4 __attribute__((ext_vector_type(4)));

static constexpr int  Bdim = 4096;
static constexpr int  Fdim = 4096;
static constexpr int  Hdim = 32768;
static constexpr long long NWELEM = 134217728ll;  // 32768*4096

// ---------------- abs-sum reduction (per-tensor absmean numerator) ----------
__global__ __launch_bounds__(256) void abssum_kernel(const float* __restrict__ src,
                                                     long long n,
                                                     double* __restrict__ out) {
  long long tid = (long long)blockIdx.x * blockDim.x + threadIdx.x;
  long long stride = (long long)gridDim.x * blockDim.x;
  double acc = 0.0;
  for (long long i = tid * 4; i < n; i += stride * 4) {
    f32x4 v = *(const f32x4*)(src + i);
    acc += (double)fabsf(v.x) + (double)fabsf(v.y) +
           (double)fabsf(v.z) + (double)fabsf(v.w);
  }
  for (int off = 32; off > 0; off >>= 1) acc += __shfl_down(acc, off, 64);
  __shared__ double red[4];
  int w = threadIdx.x >> 6, l = threadIdx.x & 63;
  if (l == 0) red[w] = acc;
  __syncthreads();
  if (threadIdx.x == 0) atomicAdd(out, red[0] + red[1] + red[2] + red[3]);
}

// ---------------- per-tensor ternary weight quantization --------------------
__global__ __launch_bounds__(256) void wquant_kernel(const float* __restrict__ src,
                                                     char* __restrict__ dst,
                                                     long long n,
                                                     const double* __restrict__ dsum,
                                                     double inv_n) {
  float mean  = fmaxf((float)(dsum[0] * inv_n), EPS_F);
  float scale = 1.0f / mean;  // reference: scale = 1/clip(mean, EPS)
  long long tid = (long long)blockIdx.x * blockDim.x + threadIdx.x;
  long long stride = (long long)gridDim.x * blockDim.x;
  for (long long i = tid * 4; i < n; i += stride * 4) {
    f32x4 v = *(const f32x4*)(src + i);
    int p = 0;
#pragma unroll
    for (int k = 0; k < 4; ++k) {
      float q = fminf(fmaxf(rintf(v[k] * scale), -1.0f), 1.0f);
      p |= (((int)q) & 0xff) << (8 * k);
    }
    *(int*)(dst + i) = p;
  }
}

// ---------------- x' = x - dec_b, per-row absmax int8 quant -----------------
__global__ __launch_bounds__(256) void xprep_kernel(const float* __restrict__ x,
                                                    const float* __restrict__ dec_b,
                                                    char* __restrict__ xq,
                                                    float* __restrict__ inv_sx) {
  int r = blockIdx.x, t = threadIdx.x;
  const float* xr = x + (long long)r * Fdim;
  float v[16];
  float mx = 0.f;
#pragma unroll
  for (int j = 0; j < 4; ++j) {
    int c = (j * 256 + t) * 4;
    f32x4 xv = *(const f32x4*)(xr + c);
    f32x4 bv = *(const f32x4*)(dec_b + c);
#pragma unroll
    for (int k = 0; k < 4; ++k) {
      float d = xv[k] - bv[k];
      v[j * 4 + k] = d;
      mx = fmaxf(mx, fabsf(d));
    }
  }
  for (int m = 1; m < 64; m <<= 1) mx = fmaxf(mx, __shfl_xor(mx, m, 64));
  __shared__ float red[4];
  int w = t >> 6, l = t & 63;
  if (l == 0) red[w] = mx;
  __syncthreads();
  mx = fmaxf(fmaxf(red[0], red[1]), fmaxf(red[2], red[3]));
  float mc = fmaxf(mx, EPS_F);
  float s = 127.0f / mc;
  char* xqr = xq + (long long)r * Fdim;
#pragma unroll
  for (int j = 0; j < 4; ++j) {
    int p = 0;
#pragma unroll
    for (int k = 0; k < 4; ++k) {
      float q = fminf(fmaxf(rintf(v[j * 4 + k] * s), -128.0f), 127.0f);
      p |= (((int)q) & 0xff) << (8 * k);
    }
    ((int*)xqr)[j * 256 + t] = p;
  }
  if (t == 0) inv_sx[r] = mc * (1.0f / 127.0f);
}

// ---------------- quantize f (relu'd, >=0) with per-row scale ---------------
__global__ __launch_bounds__(256) void fquant_kernel(const float* __restrict__ f,
                                                     char* __restrict__ fq,
                                                     const float* __restrict__ fmax) {
  int row = blockIdx.y;
  int c0 = blockIdx.x * 2048 + threadIdx.x * 8;
  float s = 127.0f / fmaxf(fmax[row], EPS_F);
  const float* fr = f + (long long)row * Hdim;
  f32x4 a = *(const f32x4*)(fr + c0);
  f32x4 b = *(const f32x4*)(fr + c0 + 4);
  int p0 = 0, p1 = 0;
#pragma unroll
  for (int k = 0; k < 4; ++k) {
    int qa = (int)fminf(fmaxf(rintf(a[k] * s), -128.f), 127.f);
    int qb = (int)fminf(fmaxf(rintf(b[k] * s), -128.f), 127.f);
    p0 |= (qa & 0xff) << (8 * k);
    p1 |= (qb & 0xff) << (8 * k);
  }
  int2 pp; pp.x = p0; pp.y = p1;
  *(int2*)(fq + (long long)row * Hdim + c0) = pp;
}

// ---------------- int8 GEMM: C[M,N] = A[M,K] @ B[N,K]^T ---------------------
// 128x128 tile, BK=64, 4 waves (2x2), each wave 64x64 via 4x4 frags of
// mfma_i32_16x16x64_i8. Double-buffered LDS staged with global_load_lds x16.
// EPIL 0: encoder (relu, write f, atomicMax row-max). EPIL 1: decoder.
__device__ __forceinline__ void gload_lds16(const char* g, char* l) {
  __builtin_amdgcn_global_load_lds((const __attribute__((address_space(1))) void*)g,
                                   (__attribute__((address_space(3))) void*)l,
                                   16, 0, 0);
}

template <int EPIL>
__global__ __launch_bounds__(256) void gemm_i8(const char* __restrict__ A,
                                               const char* __restrict__ Bm,
                                               int M, int N, int K,
                                               const float* __restrict__ rowscale,
                                               const double* __restrict__ dsum,
                                               double inv_nw,
                                               const float* __restrict__ bias,
                                               float* __restrict__ out,
                                               float* __restrict__ fmax_out) {
  __shared__ char As[2][128 * 64];
  __shared__ char Bs[2][128 * 64];

  // bijective XCD swizzle (nwg % 8 == 0 for all our grids)
  int nbx = N >> 7;
  int nwg = (M >> 7) * nbx;
  int bid = blockIdx.x;
  int cpx = nwg >> 3;
  int swz = (bid & 7) * cpx + (bid >> 3);
  int by = swz / nbx, bx = swz % nbx;

  int t = threadIdx.x;
  int w = t >> 6, l = t & 63;
  int wr = w >> 1, wc = w & 1;

  const char* Ab = A + (long long)(by * 128) * K;
  const char* Bb = Bm + (long long)(bx * 128) * K;

  i32x4 acc[4][4];
#pragma unroll
  for (int i = 0; i < 4; ++i)
#pragma unroll
    for (int j = 0; j < 4; ++j) {
      acc[i][j][0] = 0; acc[i][j][1] = 0; acc[i][j][2] = 0; acc[i][j][3] = 0;
    }

  int NT = K >> 6;

  auto stage = [&](int buf, int kt) {
#pragma unroll
    for (int i = 0; i < 2; ++i) {
      int c  = i * 256 + t;        // 16B chunk id (per-lane global addr)
      int cb = i * 256 + w * 64;   // wave-uniform LDS base chunk
      const char* ga = Ab + (long long)(c >> 2) * K + (kt << 6) + (c & 3) * 16;
      gload_lds16(ga, &As[buf][cb * 16]);
      const char* gb = Bb + (long long)(c >> 2) * K + (kt << 6) + (c & 3) * 16;
      gload_lds16(gb, &Bs[buf][cb * 16]);
    }
  };

  stage(0, 0);
  __syncthreads();

  int aoff = (wr * 64 + (l & 15)) * 64 + (l >> 4) * 16;
  int boff = (wc * 64 + (l & 15)) * 64 + (l >> 4) * 16;

  for (int kt = 0; kt < NT; ++kt) {
    int buf = kt & 1;
    if (kt + 1 < NT) stage(buf ^ 1, kt + 1);
    i32x4 af[4], bf[4];
#pragma unroll
    for (int fm = 0; fm < 4; ++fm)
      af[fm] = *(const i32x4*)(&As[buf][aoff + fm * 16 * 64]);
#pragma unroll
    for (int fn = 0; fn < 4; ++fn)
      bf[fn] = *(const i32x4*)(&Bs[buf][boff + fn * 16 * 64]);
#pragma unroll
    for (int fm = 0; fm < 4; ++fm)
#pragma unroll
      for (int fn = 0; fn < 4; ++fn)
        acc[fm][fn] = __builtin_amdgcn_mfma_i32_16x16x64_i8(af[fm], bf[fn],
                                                            acc[fm][fn], 0, 0, 0);
    __syncthreads();
  }

  float meanw = fmaxf((float)(dsum[0] * inv_nw), EPS_F);
  int row0 = by * 128 + wr * 64;
  int col0 = bx * 128 + wc * 64;

#pragma unroll
  for (int fm = 0; fm < 4; ++fm) {
#pragma unroll
    for (int r = 0; r < 4; ++r) {
      int row = row0 + fm * 16 + (l >> 4) * 4 + r;
      float sA;
      if (EPIL == 0) sA = rowscale[row] * meanw;                       // inv_sx*mean
      else           sA = fmaxf(rowscale[row], EPS_F) * (1.0f / 127.0f) * meanw;
      float rm = 0.f;
#pragma unroll
      for (int fn = 0; fn < 4; ++fn) {
        int col = col0 + fn * 16 + (l & 15);
        float val = fmaf((float)acc[fm][fn][r], sA, bias[col]);
        if (EPIL == 0) {
          val = fmaxf(val, 0.f);
          rm = fmaxf(rm, val);
        }
        out[(long long)row * N + col] = val;
      }
      if (EPIL == 0) {
        // reduce over the 16 col-lanes of this row, one atomic per row/wave
#pragma unroll
        for (int m = 1; m < 16; m <<= 1) rm = fmaxf(rm, __shfl_xor(rm, m, 64));
        if ((l & 15) == 0)
          atomicMax((int*)&fmax_out[row], __float_as_int(rm));
      }
    }
  }
}

// ---------------------------------------------------------------------------
extern "C" void kernel_launch(void* const* d_in, const int* in_sizes, int n_in,
                              void* d_out, int out_size, void* d_ws, size_t ws_size,
                              hipStream_t stream) {
  const float* x     = (const float*)d_in[0];
  const float* enc_w = (const float*)d_in[1];
  const float* enc_b = (const float*)d_in[2];
  const float* dec_w = (const float*)d_in[3];
  const float* dec_b = (const float*)d_in[4];

  float* xhat = (float*)d_out;                       // [4096, 4096]
  float* fout = (float*)d_out + 16777216ll;          // [4096, 32768]

  char* ws = (char*)d_ws;
  char*   wq     = ws;                               // enc ternary (128 MiB), later reused for fq
  char*   dq     = ws + 134217728ll;                 // dec ternary (128 MiB)
  char*   xq     = ws + 268435456ll;                 // x int8 (16 MiB)
  float*  inv_sx = (float*)(ws + 285212672ll);       // 4096 f32
  float*  fmaxv  = (float*)(ws + 285229056ll);       // 4096 f32 (needs zero init)
  double* sums   = (double*)(ws + 285245440ll);      // [0]=enc absum, [1]=dec absum

  // zero fmax + sums (ws is poisoned 0xAA before every timed call)
  hipMemsetAsync(ws + 285229056ll, 0, 16384 + 16, stream);

  abssum_kernel<<<2048, 256, 0, stream>>>(enc_w, NWELEM, &sums[0]);
  abssum_kernel<<<2048, 256, 0, stream>>>(dec_w, NWELEM, &sums[1]);

  wquant_kernel<<<4096, 256, 0, stream>>>(enc_w, wq, NWELEM, &sums[0], 1.0 / (double)NWELEM);
  wquant_kernel<<<4096, 256, 0, stream>>>(dec_w, dq, NWELEM, &sums[1], 1.0 / (double)NWELEM);

  xprep_kernel<<<4096, 256, 0, stream>>>(x, dec_b, xq, inv_sx);

  // encoder: f = relu(xq @ wq^T * scales + enc_b); track per-row max of f
  gemm_i8<0><<<(Bdim / 128) * (Hdim / 128), 256, 0, stream>>>(
      xq, wq, Bdim, Hdim, Fdim, inv_sx, &sums[0], 1.0 / (double)NWELEM,
      enc_b, fout, fmaxv);

  // quantize f into the (now free) enc ternary buffer
  fquant_kernel<<<dim3(Hdim / 2048, Bdim), 256, 0, stream>>>(fout, wq, fmaxv);

  // decoder: xhat = fq @ dq^T * scales + dec_b
  gemm_i8<1><<<(Bdim / 128) * (Fdim / 128), 256, 0, stream>>>(
      wq, dq, Bdim, Fdim, Hdim, fmaxv, &sums[1], 1.0 / (double)NWELEM,
      dec_b, xhat, nullptr);
}